// Round 14
// baseline (13250.038 us; speedup 1.0000x reference)
//
#include <hip/hip_runtime.h>
#include <cstdint>

#define Bb 256
#define Tt 512
#define Dd 128
#define Hh 512
#define BH (Bb*Hh)            // 131072
#define KGATE 640
#define NCT (Hh/16)           // 32 col-tiles per matrix
#define MATSZ (KGATE*Hh)      // 327680 elements per gate matrix slot
#define LDSB (81920 + 32768 + 3*16*33*4)   // 121,024 B — proven working size

typedef unsigned short ushort_t;
typedef _Float16 h16x8 __attribute__((ext_vector_type(8)));
typedef unsigned short u16x8 __attribute__((ext_vector_type(8)));
typedef float f32x4 __attribute__((ext_vector_type(4)));

static __device__ inline ushort_t f2h(float f){
    _Float16 h = (_Float16)f;
    return __builtin_bit_cast(ushort_t, h);
}
static __device__ inline float h2f(ushort_t u){
    return (float)__builtin_bit_cast(_Float16, u);
}
static __device__ inline float sigmoidf_(float x){ return 1.f/(1.f+__expf(-x)); }
static __device__ inline float tanhf_(float x){
    float ax = fabsf(x);
    float t = __expf(-2.f*ax);
    float r = (1.f - t)/(1.f + t);
    return copysignf(r, x);
}
static __device__ inline h16x8 load_x_frag(const float* xp){
    f32x4 v0 = *reinterpret_cast<const f32x4*>(xp);
    f32x4 v1 = *reinterpret_cast<const f32x4*>(xp + 4);
    u16x8 tmp;
    #pragma unroll
    for (int j = 0; j < 4; ++j){ tmp[j] = f2h(v0[j]); tmp[4+j] = f2h(v1[j]); }
    return __builtin_bit_cast(h16x8, tmp);
}

// ---- device-coherent (agent-scope, relaxed) accessors ----
static __device__ inline void st_u32(uint32_t* p, uint32_t v){
    __hip_atomic_store(p, v, __ATOMIC_RELAXED, __HIP_MEMORY_SCOPE_AGENT);
}
static __device__ inline uint32_t ld_u32(const uint32_t* p){
    return __hip_atomic_load(p, __ATOMIC_RELAXED, __HIP_MEMORY_SCOPE_AGENT);
}

// Pack one weight matrix (optionally stacked [W(128 rows); U(512 rows)]) into
// MFMA B-fragment order (fp16): elem(lane,j) = M[kb*32 + (lane>>4)*8 + j][ct*16 + (lane&15)]
__global__ void pack_mat(const float* __restrict__ Wm, const float* __restrict__ Um,
                         int Ktot, ushort_t* __restrict__ dst){
    int total = Ktot * 64;  // groups of 8 fp16
    for (int g = blockIdx.x*blockDim.x + threadIdx.x; g < total; g += gridDim.x*blockDim.x){
        int kb   = g >> 11;
        int rem  = g & 2047;
        int ct   = rem >> 6;
        int lane = rem & 63;
        int k0   = kb*32 + ((lane >> 4) << 3);
        int col  = (ct << 4) + (lane & 15);
        u16x8 o8;
        #pragma unroll
        for (int j = 0; j < 8; ++j){
            int k = k0 + j;
            float v;
            if (Um) v = (k < Dd) ? Wm[k*Hh + col] : Um[(k - Dd)*Hh + col];
            else    v = Wm[k*Hh + col];
            o8[j] = f2h(v);
        }
        *reinterpret_cast<u16x8*>(dst + (size_t)g*8) = o8;
    }
}

__global__ void init_state2(ushort_t* h16, uint32_t* bar){
    int i = blockIdx.x*blockDim.x + threadIdx.x;
    if (i < BH) h16[i] = 0;
    if (i < 8192) bar[i] = 0;   // 4 group counters at 128B stride (rest padding)
}

struct PK {
    const ushort_t* wpack;
    const float* X0; const float* X1; const float* X2;
    const float* bC0; const float* bC1; const float* bC2;
    const float* bI0; const float* bI1; const float* bI2;
    const float* bF; const float* bO; const float* b_a;
    ushort_t* hbf;    // fp16, chunked [16 c2][256 rows][32 cols]
    ushort_t* l16;    // fp16, chunked [3 s][16 cs][256 rows][32 cols]
    ushort_t* fo16;   // fp16, chunked [4 g][2 fu][8 cfo][64 rows][64 cols]
    uint32_t* bar; float* out;
};

// Single-counter group barrier: each block's tid0 does one relaxed agent-scope
// fetch_add on the group's (128B-isolated) counter, then polls THAT ONE LINE
// until all 64 arrivals of this phase are in (monotone target, never reset).
// Other waves park at s_barrier. Producers' scoped write-through stores were
// drained by the vmcnt(0) before s_barrier; the trailing agent acquire fence
// (L1+L2 inv) makes plain cached consumer loads see fresh MALL data.
// All ingredients proven: fetch_add+single-poll (R2), fence placement (R6/R13).
static __device__ inline void group_barrier(uint32_t* gctr, uint32_t target){
    __builtin_amdgcn_fence(__ATOMIC_RELEASE, "workgroup");
    __syncthreads();
    if (threadIdx.x == 0){
        __hip_atomic_fetch_add(gctr, 1u, __ATOMIC_RELAXED, __HIP_MEMORY_SCOPE_AGENT);
        while (__hip_atomic_load(gctr, __ATOMIC_RELAXED, __HIP_MEMORY_SCOPE_AGENT) < target)
            __builtin_amdgcn_s_sleep(1);
    }
    __syncthreads();
    __builtin_amdgcn_fence(__ATOMIC_ACQUIRE, "agent");
}

// 256 blocks x 256 threads, cooperative. Group g = bid>>6 owns batch rows [g*64, g*64+64).
// gb 0..47: paired gate blocks (stream s=gb>>4, 32-col slice cs=gb&15): c-mat + i-mat.
// gb 48..55: f-gate (64-col slice). gb 56..63: o-gate (64-col slice).
// Phase B (all blocks): rows rs*16, cols c2*32; c state in registers.
__global__ __launch_bounds__(256, 1) void lstm_persistent(PK A){
    extern __shared__ char lds[];
    ushort_t* Wlds  = (ushort_t*)lds;                    // 81920 B
    ushort_t* WaLds = (ushort_t*)(lds + 81920);          // 32768 B
    float*    u_lds = (float*)(lds + 81920 + 32768);     // scratch: 6336 B
    ushort_t* srep  = (ushort_t*)u_lds;                  // u16 repack view (max 4096 B used)

    const int bid = blockIdx.x;
    const int g   = bid >> 6;
    const int gb  = bid & 63;
    const int tid = threadIdx.x;
    const int lane = tid & 63;
    const int wave = tid >> 6;
    const int r15  = lane & 15;
    const int khi  = (lane >> 4) << 3;
    const int quad = (lane >> 4) << 2;
    const int grow0 = g << 6;

    const bool paired = (gb < 48);
    const int s   = gb >> 4;
    const int cs  = gb & 15;
    const int fu  = (gb >= 56) ? 1 : 0;
    const int cfo = (gb - 48) & 7;

    // ---- stage weights into LDS (once) ----
    if (paired){
        const ushort_t* base0 = A.wpack + (size_t)(4 + s)*MATSZ;  // c-mat
        const ushort_t* base1 = A.wpack + (size_t)s*MATSZ;        // i-mat
        for (int u = tid; u < 80*64; u += 256){
            int ch = u >> 6, un = u & 63;
            int m2 = (ch >= 40) ? 1 : 0;
            int rem = ch - m2*40;
            int kb = rem >> 1, j = rem & 1;
            const ushort_t* src = (m2 == 0 ? base0 : base1)
                                + ((size_t)(kb*NCT + cs*2 + j)*64 + un)*8;
            *reinterpret_cast<u16x8*>(Wlds + ((size_t)ch*64 + un)*8)
                = *reinterpret_cast<const u16x8*>(src);
        }
    } else {
        const ushort_t* base = A.wpack + (size_t)(fu == 0 ? 3 : 7)*MATSZ;
        for (int u = tid; u < 80*64; u += 256){
            int ch = u >> 6, un = u & 63;
            int kb = ch >> 2, j = ch & 3;
            const ushort_t* src = base + ((size_t)(kb*NCT + cfo*4 + j)*64 + un)*8;
            *reinterpret_cast<u16x8*>(Wlds + ((size_t)ch*64 + un)*8)
                = *reinterpret_cast<const u16x8*>(src);
        }
    }
    const int rs = gb >> 4, c2 = gb & 15;   // phase-B tile
    {
        const ushort_t* base = A.wpack + (size_t)8*MATSZ;
        for (int u = tid; u < 32*64; u += 256){
            int ch = u >> 6, un = u & 63;
            int kb = ch >> 1, j = ch & 1;
            const ushort_t* src = base + ((size_t)(kb*NCT + c2*2 + j)*64 + un)*8;
            *reinterpret_cast<u16x8*>(WaLds + ((size_t)ch*64 + un)*8)
                = *reinterpret_cast<const u16x8*>(src);
        }
    }
    __syncthreads();

    // ---- per-thread persistent state ----
    float biasA0[4] = {0,0,0,0}, biasA1[2] = {0,0};
    if (paired){
        const float* bCs = (s == 0) ? A.bC0 : (s == 1) ? A.bC1 : A.bC2;
        const float* bIs = (s == 0) ? A.bI0 : (s == 1) ? A.bI1 : A.bI2;
        #pragma unroll
        for (int fj = 0; fj < 2; ++fj){
            int col = cs*32 + fj*16 + r15;
            biasA0[fj] = bCs[col];
            biasA1[fj] = bIs[col];
        }
    } else {
        const float* bb = fu ? A.bO : A.bF;
        #pragma unroll
        for (int fj = 0; fj < 4; ++fj)
            biasA0[fj] = bb[cfo*64 + fj*16 + r15];
    }
    const int rowE = tid >> 5;          // 0..7
    const int colE = tid & 31;
    const int gcol = c2*32 + colE;
    const int growE0 = grow0 + rs*16 + rowE;
    const int growE1 = growE0 + 8;
    const float ba = A.b_a[gcol];
    float creg0 = 0.f, creg1 = 0.f;

    const float* Xs = paired ? ((s == 0) ? A.X0 : (s == 1) ? A.X1 : A.X2) : A.X0;
    uint32_t* gctr = A.bar + g*32;      // one counter per group, 128B apart
    const int arow = grow0 + wave*16 + r15;

    // elementwise read indices (fp16 chunked buffers)
    const int cfoE = gcol >> 6;          // 64-col chunk for f/o
    const int colF = gcol & 63;

    for (int t = 0; t < Tt; ++t){
        // ================= phase A: gate GEMMs =================
        if (paired){
            f32x4 a0[2] = {{0.f,0.f,0.f,0.f},{0.f,0.f,0.f,0.f}};
            f32x4 a1[2] = {{0.f,0.f,0.f,0.f},{0.f,0.f,0.f,0.f}};
            const float* xp = Xs + ((size_t)arow*Tt + t)*Dd + khi;
            #pragma unroll
            for (int kb = 0; kb < KGATE/32; ++kb){
                h16x8 a;
                if (kb < 4) a = load_x_frag(xp + kb*32);
                else        a = *reinterpret_cast<const h16x8*>(
                                  A.hbf + (((size_t)(kb-4)*Bb + arow)*32 + khi));
                #pragma unroll
                for (int fj = 0; fj < 2; ++fj){
                    h16x8 b0 = *reinterpret_cast<const h16x8*>(Wlds + ((size_t)(kb*2 + fj))*512 + lane*8);
                    a0[fj] = __builtin_amdgcn_mfma_f32_16x16x32_f16(a, b0, a0[fj], 0, 0, 0);
                    h16x8 b1 = *reinterpret_cast<const h16x8*>(Wlds + ((size_t)((20 + kb)*2 + fj))*512 + lane*8);
                    a1[fj] = __builtin_amdgcn_mfma_f32_16x16x32_f16(a, b1, a1[fj], 0, 0, 0);
                }
            }
            // repack l (fp16) into LDS (64x32 = 4096 B), then coop full-line scoped stores
            #pragma unroll
            for (int fj = 0; fj < 2; ++fj)
            #pragma unroll
            for (int r = 0; r < 4; ++r){
                int lrow = wave*16 + quad + r;
                float l = tanhf_(a0[fj][r] + biasA0[fj]) * sigmoidf_(a1[fj][r] + biasA1[fj]);
                srep[lrow*32 + fj*16 + r15] = f2h(l);
            }
            __syncthreads();
            {   // block-exclusive chunk [s][cs]: rows grow0..+64, 16 u32/row
                uint32_t* dst = (uint32_t*)A.l16 + ((size_t)(s*16 + cs)*Bb + grow0)*16;
                const uint32_t* src = (const uint32_t*)srep;
                #pragma unroll
                for (int k2 = 0; k2 < 4; ++k2){
                    int idx = tid + k2*256;
                    int lrow = idx >> 4, cp = idx & 15;
                    st_u32(dst + (size_t)lrow*16 + cp, src[idx]);
                }
            }
        } else {
            f32x4 ac[4] = {{0.f,0.f,0.f,0.f},{0.f,0.f,0.f,0.f},{0.f,0.f,0.f,0.f},{0.f,0.f,0.f,0.f}};
            const float* xp = Xs + ((size_t)arow*Tt + t)*Dd + khi;
            #pragma unroll
            for (int kb = 0; kb < KGATE/32; ++kb){
                h16x8 a;
                if (kb < 4) a = load_x_frag(xp + kb*32);
                else        a = *reinterpret_cast<const h16x8*>(
                                  A.hbf + (((size_t)(kb-4)*Bb + arow)*32 + khi));
                #pragma unroll
                for (int fj = 0; fj < 4; ++fj){
                    h16x8 b = *reinterpret_cast<const h16x8*>(Wlds + ((size_t)(kb*4 + fj))*512 + lane*8);
                    ac[fj] = __builtin_amdgcn_mfma_f32_16x16x32_f16(a, b, ac[fj], 0, 0, 0);
                }
            }
            // repack f/o in TWO 64x32 passes (4096 B each — fits 6336 B scratch).
            // Chunk layout [64 rows][64 cols]: pass p covers cols p*32..p*32+32.
            uint32_t* dstc = (uint32_t*)A.fo16 + (size_t)((g*2 + fu)*8 + cfo)*2048;
            #pragma unroll
            for (int p = 0; p < 2; ++p){
                #pragma unroll
                for (int fj2 = 0; fj2 < 2; ++fj2){
                    int fj = p*2 + fj2;
                    #pragma unroll
                    for (int r = 0; r < 4; ++r){
                        int lrow = wave*16 + quad + r;
                        srep[lrow*32 + fj2*16 + r15] = f2h(sigmoidf_(ac[fj][r] + biasA0[fj]));
                    }
                }
                __syncthreads();
                {   // store 64 rows x 32 cols (16 u32/row) at col-offset p*32 (p*16 u32)
                    const uint32_t* src = (const uint32_t*)srep;
                    #pragma unroll
                    for (int k2 = 0; k2 < 4; ++k2){
                        int idx = tid + k2*256;          // 0..1023
                        int lrow = idx >> 4, cp = idx & 15;
                        st_u32(dstc + (size_t)lrow*32 + p*16 + cp, src[idx]);
                    }
                }
                __syncthreads();   // srep reads done before next pass overwrites
            }
        }

        group_barrier(gctr, (uint32_t)(64*(2*t + 1)));

        // ================= phase B: W_a GEMMs + blend + cell update =================
        if (wave < 3){
            f32x4 acB[2] = {{0.f,0.f,0.f,0.f},{0.f,0.f,0.f,0.f}};
            const int brow = grow0 + rs*16 + r15;
            #pragma unroll
            for (int kb = 0; kb < Hh/32; ++kb){
                h16x8 a = *reinterpret_cast<const h16x8*>(
                    A.l16 + (((size_t)(wave*16 + kb)*Bb + brow)*32 + khi));
                #pragma unroll
                for (int fj = 0; fj < 2; ++fj){
                    h16x8 b = *reinterpret_cast<const h16x8*>(WaLds + ((size_t)(kb*2 + fj))*512 + lane*8);
                    acB[fj] = __builtin_amdgcn_mfma_f32_16x16x32_f16(a, b, acB[fj], 0, 0, 0);
                }
            }
            #pragma unroll
            for (int fj = 0; fj < 2; ++fj)
            #pragma unroll
            for (int r = 0; r < 4; ++r){
                int rowL = quad + r;
                u_lds[(wave*16 + rowL)*33 + fj*16 + r15] = acB[fj][r];
            }
        }
        __syncthreads();

        float hn0, hn1;
        {   // elementwise: 2 elems/thread; c in registers; plain cached loads
            #pragma unroll
            for (int e = 0; e < 2; ++e){
                int rowX = rowE + e*8;
                int growX = e ? growE1 : growE0;
                float cv = e ? creg1 : creg0;
                float u0 = u_lds[(0*16 + rowX)*33 + colE];
                float u1 = u_lds[(1*16 + rowX)*33 + colE];
                float u2 = u_lds[(2*16 + rowX)*33 + colE];
                float e0 = __expf(tanhf_(u0*cv + ba));
                float e1 = __expf(tanhf_(u1*cv + ba));
                float e2 = __expf(tanhf_(u2*cv + ba));
                float inv = 1.f/(e0 + e1 + e2);
                size_t lidx = ((size_t)c2*Bb + growX)*32 + colE;   // within stream chunk
                float l0 = h2f(A.l16[(size_t)(0*16)*Bb*32 + lidx]);
                float l1 = h2f(A.l16[(size_t)(1*16)*Bb*32 + lidx]);
                float l2 = h2f(A.l16[(size_t)(2*16)*Bb*32 + lidx]);
                size_t fidx = (size_t)((g*2 + 0)*8 + cfoE)*4096 + (size_t)(growX - grow0)*64 + colF;
                size_t oidx = (size_t)((g*2 + 1)*8 + cfoE)*4096 + (size_t)(growX - grow0)*64 + colF;
                float fg = h2f(A.fo16[fidx]);
                float og = h2f(A.fo16[oidx]);
                float L = (e0*l0 + e1*l1 + e2*l2)*inv;
                float cn = fg*cv + L;
                float hn = og*tanhf_(cn);
                if (e) creg1 = cn; else creg0 = cn;
                __builtin_nontemporal_store(hn, &A.out[(size_t)BH + ((size_t)growX*Tt + t)*Hh + gcol]);
                if (t == Tt - 1) __builtin_nontemporal_store(hn, &A.out[(size_t)growX*Hh + gcol]);
                if (e) hn1 = hn; else hn0 = hn;
            }
        }
        __syncthreads();                       // everyone done reading u_lds
        {   // repack h tile to fp16 and store into block-exclusive chunk
            srep[rowE*32 + colE]      = f2h(hn0);
            srep[(rowE+8)*32 + colE]  = f2h(hn1);
            __syncthreads();
            uint32_t* dst = (uint32_t*)A.hbf + ((size_t)c2*Bb + grow0 + rs*16)*16;
            int lr = tid >> 4, cp = tid & 15;
            st_u32(dst + (size_t)lr*16 + cp, ((const uint32_t*)srep)[tid]);
        }

        if (t != Tt - 1) group_barrier(gctr, (uint32_t)(64*(2*t + 2)));
    }
}

extern "C" void kernel_launch(void* const* d_in, const int* in_sizes, int n_in,
                              void* d_out, int out_size, void* d_ws, size_t ws_size,
                              hipStream_t stream){
    const float* in[29];
    for (int i = 0; i < 29; ++i) in[i] = (const float*)d_in[i];

    char* ws = (char*)d_ws;
    ushort_t* wpack = (ushort_t*)(ws + 0);         // 5,898,240 B (fp16)
    ushort_t* h16   = (ushort_t*)(ws + 5898240);   //   262,144 B (chunked fp16)
    ushort_t* l16   = (ushort_t*)(ws + 6160384);   //   786,432 B (chunked fp16)
    ushort_t* fo16  = (ushort_t*)(ws + 6946816);   //   524,288 B (chunked fp16)
    uint32_t* bar   = (uint32_t*)(ws + 7471104);   //    32,768 B (padded counters)
    // total ~7.5 MB of d_ws

    // mats: 0:i 1:i_p 2:i_n 3:f 4:c 5:c_p 6:c_n 7:o (K=640, [W;U]) ; 8: W_a (K=512)
    static const int WI[9] = {0, 3, 6, 9, 12, 15, 18, 21, 24};
    static const int UI[9] = {1, 4, 7, 10, 13, 16, 19, 22, -1};
    for (int m = 0; m < 9; ++m){
        int Ktot = (m == 8) ? Hh : KGATE;
        const float* Um = (m == 8) ? nullptr : in[UI[m]];
        int groups = Ktot*64;
        pack_mat<<<dim3((groups + 255)/256), dim3(256), 0, stream>>>(
            in[WI[m]], Um, Ktot, wpack + (size_t)m*MATSZ);
    }
    init_state2<<<dim3(BH/256), dim3(256), 0, stream>>>(h16, bar);

    PK pk;
    pk.wpack = wpack;
    pk.X0 = in[26]; pk.X1 = in[27]; pk.X2 = in[28];
    pk.bC0 = in[14]; pk.bC1 = in[17]; pk.bC2 = in[20];
    pk.bI0 = in[2];  pk.bI1 = in[5];  pk.bI2 = in[8];
    pk.bF = in[11]; pk.bO = in[23]; pk.b_a = in[25];
    pk.hbf = h16; pk.l16 = l16; pk.fo16 = fo16;
    pk.bar = bar; pk.out = (float*)d_out;

    hipFuncSetAttribute((const void*)lstm_persistent,
                        hipFuncAttributeMaxDynamicSharedMemorySize, LDSB);
    void* args[] = { &pk };
    hipLaunchCooperativeKernel((const void*)lstm_persistent,
                               dim3(256), dim3(256), args, LDSB, stream);
}

// Round 16
// 9555.988 us; speedup vs baseline: 1.3866x; 1.3866x over previous
//
#include <hip/hip_runtime.h>
#include <cstdint>

#define Bb 256
#define Tt 512
#define Dd 128
#define Hh 512
#define BH (Bb*Hh)            // 131072
#define KGATE 640
#define NCT (Hh/16)           // 32 col-tiles per matrix
#define MATSZ (KGATE*Hh)      // 327680 elements per gate matrix slot
#define LDSB (81920 + 32768 + 3*16*33*4)   // 121,024 B — proven working size

typedef unsigned short ushort_t;
typedef _Float16 h16x8 __attribute__((ext_vector_type(8)));
typedef unsigned short u16x8 __attribute__((ext_vector_type(8)));
typedef float f32x4 __attribute__((ext_vector_type(4)));

static __device__ inline ushort_t f2h(float f){
    _Float16 h = (_Float16)f;
    return __builtin_bit_cast(ushort_t, h);
}
static __device__ inline float h2f(ushort_t u){
    return (float)__builtin_bit_cast(_Float16, u);
}
static __device__ inline float sigmoidf_(float x){ return 1.f/(1.f+__expf(-x)); }
static __device__ inline float tanhf_(float x){
    float ax = fabsf(x);
    float t = __expf(-2.f*ax);
    float r = (1.f - t)/(1.f + t);
    return copysignf(r, x);
}
static __device__ inline h16x8 load_x_frag(const float* xp){
    f32x4 v0 = *reinterpret_cast<const f32x4*>(xp);
    f32x4 v1 = *reinterpret_cast<const f32x4*>(xp + 4);
    u16x8 tmp;
    #pragma unroll
    for (int j = 0; j < 4; ++j){ tmp[j] = f2h(v0[j]); tmp[4+j] = f2h(v1[j]); }
    return __builtin_bit_cast(h16x8, tmp);
}

// ---- device-coherent (agent-scope, relaxed) accessors — R5-proven family ----
static __device__ inline void st_u32(uint32_t* p, uint32_t v){
    __hip_atomic_store(p, v, __ATOMIC_RELAXED, __HIP_MEMORY_SCOPE_AGENT);
}
static __device__ inline uint32_t ld_u32(const uint32_t* p){
    return __hip_atomic_load(p, __ATOMIC_RELAXED, __HIP_MEMORY_SCOPE_AGENT);
}
static __device__ inline ushort_t ld_u16s(const ushort_t* p){
    return __hip_atomic_load(p, __ATOMIC_RELAXED, __HIP_MEMORY_SCOPE_AGENT);
}
static __device__ inline h16x8 ld_frag32(const uint32_t* q){
    union { uint32_t w[4]; h16x8 v; } u;
    u.w[0] = ld_u32(q + 0); u.w[1] = ld_u32(q + 1);
    u.w[2] = ld_u32(q + 2); u.w[3] = ld_u32(q + 3);
    return u.v;
}

// Pack one weight matrix (optionally stacked [W(128 rows); U(512 rows)]) into
// MFMA B-fragment order (fp16): elem(lane,j) = M[kb*32 + (lane>>4)*8 + j][ct*16 + (lane&15)]
__global__ void pack_mat(const float* __restrict__ Wm, const float* __restrict__ Um,
                         int Ktot, ushort_t* __restrict__ dst){
    int total = Ktot * 64;  // groups of 8 fp16
    for (int g = blockIdx.x*blockDim.x + threadIdx.x; g < total; g += gridDim.x*blockDim.x){
        int kb   = g >> 11;
        int rem  = g & 2047;
        int ct   = rem >> 6;
        int lane = rem & 63;
        int k0   = kb*32 + ((lane >> 4) << 3);
        int col  = (ct << 4) + (lane & 15);
        u16x8 o8;
        #pragma unroll
        for (int j = 0; j < 8; ++j){
            int k = k0 + j;
            float v;
            if (Um) v = (k < Dd) ? Wm[k*Hh + col] : Um[(k - Dd)*Hh + col];
            else    v = Wm[k*Hh + col];
            o8[j] = f2h(v);
        }
        *reinterpret_cast<u16x8*>(dst + (size_t)g*8) = o8;
    }
}

__global__ void init_state2(ushort_t* h16, uint32_t* bar){
    int i = blockIdx.x*blockDim.x + threadIdx.x;
    if (i < BH) h16[i] = 0;
    if (i < 8192) bar[i] = 0;   // 4 groups x 64 block-flags x 32 u32 padding
}

struct PK {
    const ushort_t* wpack;
    const float* X0; const float* X1; const float* X2;
    const float* bC0; const float* bC1; const float* bC2;
    const float* bI0; const float* bI1; const float* bI2;
    const float* bF; const float* bO; const float* b_a;
    ushort_t* hbf;    // fp16, chunked [16 c2][256 rows][32 cols]
    ushort_t* l16;    // fp16, chunked [3 s][16 cs][256 rows][32 cols]
    ushort_t* fo16;   // fp16, chunked [4 g][2 fu][8 cfo][64 rows][64 cols]
    uint32_t* bar; float* out;
};

// Fence-free flag barrier (R5 memory model on R13's clean layout): flags padded
// to 128B; producers' agent-scope write-through stores are drained by the
// vmcnt(0) the compiler emits before s_barrier, so data is at MALL before the
// flag publish. Consumers read exchange buffers with agent-scope relaxed loads
// (MALL-coherent) — NO L2-invalidate fence, no refetch storm. Workgroup fences
// are compile-time ordering only.
static __device__ inline void group_barrier(uint32_t* gflags, int gb, uint32_t val){
    __builtin_amdgcn_fence(__ATOMIC_RELEASE, "workgroup");
    __syncthreads();
    if (threadIdx.x == 0) st_u32(&gflags[gb*32], val);
    if (threadIdx.x < 64){
        while (ld_u32(&gflags[threadIdx.x*32]) < val)
            __builtin_amdgcn_s_sleep(1);
    }
    __syncthreads();
    __builtin_amdgcn_fence(__ATOMIC_ACQUIRE, "workgroup");
}

// 256 blocks x 256 threads, cooperative. Group g = bid>>6 owns batch rows [g*64, g*64+64).
// gb 0..47: paired gate blocks (stream s=gb>>4, 32-col slice cs=gb&15): c-mat + i-mat.
// gb 48..55: f-gate (64-col slice). gb 56..63: o-gate (64-col slice).
// Phase B (all blocks): rows rs*16, cols c2*32; c state in registers.
__global__ __launch_bounds__(256, 1) void lstm_persistent(PK A){
    extern __shared__ char lds[];
    ushort_t* Wlds  = (ushort_t*)lds;                    // 81920 B
    ushort_t* WaLds = (ushort_t*)(lds + 81920);          // 32768 B
    float*    u_lds = (float*)(lds + 81920 + 32768);     // scratch: 6336 B
    ushort_t* srep  = (ushort_t*)u_lds;                  // u16 repack view (max 4096 B used)

    const int bid = blockIdx.x;
    const int g   = bid >> 6;
    const int gb  = bid & 63;
    const int tid = threadIdx.x;
    const int lane = tid & 63;
    const int wave = tid >> 6;
    const int r15  = lane & 15;
    const int khi  = (lane >> 4) << 3;
    const int quad = (lane >> 4) << 2;
    const int grow0 = g << 6;

    const bool paired = (gb < 48);
    const int s   = gb >> 4;
    const int cs  = gb & 15;
    const int fu  = (gb >= 56) ? 1 : 0;
    const int cfo = (gb - 48) & 7;

    const uint32_t* hbf32 = (const uint32_t*)A.hbf;
    const uint32_t* l32   = (const uint32_t*)A.l16;

    // ---- stage weights into LDS (once) ----
    if (paired){
        const ushort_t* base0 = A.wpack + (size_t)(4 + s)*MATSZ;  // c-mat
        const ushort_t* base1 = A.wpack + (size_t)s*MATSZ;        // i-mat
        for (int u = tid; u < 80*64; u += 256){
            int ch = u >> 6, un = u & 63;
            int m2 = (ch >= 40) ? 1 : 0;
            int rem = ch - m2*40;
            int kb = rem >> 1, j = rem & 1;
            const ushort_t* src = (m2 == 0 ? base0 : base1)
                                + ((size_t)(kb*NCT + cs*2 + j)*64 + un)*8;
            *reinterpret_cast<u16x8*>(Wlds + ((size_t)ch*64 + un)*8)
                = *reinterpret_cast<const u16x8*>(src);
        }
    } else {
        const ushort_t* base = A.wpack + (size_t)(fu == 0 ? 3 : 7)*MATSZ;
        for (int u = tid; u < 80*64; u += 256){
            int ch = u >> 6, un = u & 63;
            int kb = ch >> 2, j = ch & 3;
            const ushort_t* src = base + ((size_t)(kb*NCT + cfo*4 + j)*64 + un)*8;
            *reinterpret_cast<u16x8*>(Wlds + ((size_t)ch*64 + un)*8)
                = *reinterpret_cast<const u16x8*>(src);
        }
    }
    const int rs = gb >> 4, c2 = gb & 15;   // phase-B tile
    {
        const ushort_t* base = A.wpack + (size_t)8*MATSZ;
        for (int u = tid; u < 32*64; u += 256){
            int ch = u >> 6, un = u & 63;
            int kb = ch >> 1, j = ch & 1;
            const ushort_t* src = base + ((size_t)(kb*NCT + c2*2 + j)*64 + un)*8;
            *reinterpret_cast<u16x8*>(WaLds + ((size_t)ch*64 + un)*8)
                = *reinterpret_cast<const u16x8*>(src);
        }
    }
    __syncthreads();

    // ---- per-thread persistent state ----
    float biasA0[4] = {0,0,0,0}, biasA1[2] = {0,0};
    if (paired){
        const float* bCs = (s == 0) ? A.bC0 : (s == 1) ? A.bC1 : A.bC2;
        const float* bIs = (s == 0) ? A.bI0 : (s == 1) ? A.bI1 : A.bI2;
        #pragma unroll
        for (int fj = 0; fj < 2; ++fj){
            int col = cs*32 + fj*16 + r15;
            biasA0[fj] = bCs[col];
            biasA1[fj] = bIs[col];
        }
    } else {
        const float* bb = fu ? A.bO : A.bF;
        #pragma unroll
        for (int fj = 0; fj < 4; ++fj)
            biasA0[fj] = bb[cfo*64 + fj*16 + r15];
    }
    const int rowE = tid >> 5;          // 0..7
    const int colE = tid & 31;
    const int gcol = c2*32 + colE;
    const int growE0 = grow0 + rs*16 + rowE;
    const int growE1 = growE0 + 8;
    const float ba = A.b_a[gcol];
    float creg0 = 0.f, creg1 = 0.f;

    const float* Xs = paired ? ((s == 0) ? A.X0 : (s == 1) ? A.X1 : A.X2) : A.X0;
    uint32_t* gflags = A.bar + g*2048;           // [64][32]
    const int arow = grow0 + wave*16 + r15;

    // elementwise read indices (fp16 chunked buffers)
    const int cfoE = gcol >> 6;          // 64-col chunk for f/o
    const int colF = gcol & 63;

    for (int t = 0; t < Tt; ++t){
        // ================= phase A: gate GEMMs =================
        if (paired){
            f32x4 a0[2] = {{0.f,0.f,0.f,0.f},{0.f,0.f,0.f,0.f}};
            f32x4 a1[2] = {{0.f,0.f,0.f,0.f},{0.f,0.f,0.f,0.f}};
            const float* xp = Xs + ((size_t)arow*Tt + t)*Dd + khi;
            #pragma unroll
            for (int kb = 0; kb < KGATE/32; ++kb){
                h16x8 a;
                if (kb < 4) a = load_x_frag(xp + kb*32);
                else        a = ld_frag32(hbf32 + ((((size_t)(kb-4)*Bb + arow)*32 + khi) >> 1));
                #pragma unroll
                for (int fj = 0; fj < 2; ++fj){
                    h16x8 b0 = *reinterpret_cast<const h16x8*>(Wlds + ((size_t)(kb*2 + fj))*512 + lane*8);
                    a0[fj] = __builtin_amdgcn_mfma_f32_16x16x32_f16(a, b0, a0[fj], 0, 0, 0);
                    h16x8 b1 = *reinterpret_cast<const h16x8*>(Wlds + ((size_t)((20 + kb)*2 + fj))*512 + lane*8);
                    a1[fj] = __builtin_amdgcn_mfma_f32_16x16x32_f16(a, b1, a1[fj], 0, 0, 0);
                }
            }
            // repack l (fp16) into LDS (64x32 = 4096 B), then coop full-line scoped stores
            #pragma unroll
            for (int fj = 0; fj < 2; ++fj)
            #pragma unroll
            for (int r = 0; r < 4; ++r){
                int lrow = wave*16 + quad + r;
                float l = tanhf_(a0[fj][r] + biasA0[fj]) * sigmoidf_(a1[fj][r] + biasA1[fj]);
                srep[lrow*32 + fj*16 + r15] = f2h(l);
            }
            __syncthreads();
            {   // block-exclusive chunk [s][cs]: rows grow0..+64, 16 u32/row
                uint32_t* dst = (uint32_t*)A.l16 + ((size_t)(s*16 + cs)*Bb + grow0)*16;
                const uint32_t* src = (const uint32_t*)srep;
                #pragma unroll
                for (int k2 = 0; k2 < 4; ++k2){
                    int idx = tid + k2*256;
                    int lrow = idx >> 4, cp = idx & 15;
                    st_u32(dst + (size_t)lrow*16 + cp, src[idx]);
                }
            }
        } else {
            f32x4 ac[4] = {{0.f,0.f,0.f,0.f},{0.f,0.f,0.f,0.f},{0.f,0.f,0.f,0.f},{0.f,0.f,0.f,0.f}};
            const float* xp = Xs + ((size_t)arow*Tt + t)*Dd + khi;
            #pragma unroll
            for (int kb = 0; kb < KGATE/32; ++kb){
                h16x8 a;
                if (kb < 4) a = load_x_frag(xp + kb*32);
                else        a = ld_frag32(hbf32 + ((((size_t)(kb-4)*Bb + arow)*32 + khi) >> 1));
                #pragma unroll
                for (int fj = 0; fj < 4; ++fj){
                    h16x8 b = *reinterpret_cast<const h16x8*>(Wlds + ((size_t)(kb*4 + fj))*512 + lane*8);
                    ac[fj] = __builtin_amdgcn_mfma_f32_16x16x32_f16(a, b, ac[fj], 0, 0, 0);
                }
            }
            // repack f/o in TWO 64x32 passes (4096 B each — fits scratch).
            // Chunk layout [64 rows][64 cols]: pass p covers cols p*32..p*32+32.
            uint32_t* dstc = (uint32_t*)A.fo16 + (size_t)((g*2 + fu)*8 + cfo)*2048;
            #pragma unroll
            for (int p = 0; p < 2; ++p){
                #pragma unroll
                for (int fj2 = 0; fj2 < 2; ++fj2){
                    int fj = p*2 + fj2;
                    #pragma unroll
                    for (int r = 0; r < 4; ++r){
                        int lrow = wave*16 + quad + r;
                        srep[lrow*32 + fj2*16 + r15] = f2h(sigmoidf_(ac[fj][r] + biasA0[fj]));
                    }
                }
                __syncthreads();
                {   // store 64 rows x 32 cols (16 u32/row) at col-offset p*32 (p*16 u32)
                    const uint32_t* src = (const uint32_t*)srep;
                    #pragma unroll
                    for (int k2 = 0; k2 < 4; ++k2){
                        int idx = tid + k2*256;          // 0..1023
                        int lrow = idx >> 4, cp = idx & 15;
                        st_u32(dstc + (size_t)lrow*32 + p*16 + cp, src[idx]);
                    }
                }
                __syncthreads();   // srep reads done before next pass overwrites
            }
        }

        group_barrier(gflags, gb, (uint32_t)(2*t + 1));

        // ================= phase B: W_a GEMMs + blend + cell update =================
        if (wave < 3){
            f32x4 acB[2] = {{0.f,0.f,0.f,0.f},{0.f,0.f,0.f,0.f}};
            const int brow = grow0 + rs*16 + r15;
            #pragma unroll
            for (int kb = 0; kb < Hh/32; ++kb){
                h16x8 a = ld_frag32(l32 + ((((size_t)(wave*16 + kb)*Bb + brow)*32 + khi) >> 1));
                #pragma unroll
                for (int fj = 0; fj < 2; ++fj){
                    h16x8 b = *reinterpret_cast<const h16x8*>(WaLds + ((size_t)(kb*2 + fj))*512 + lane*8);
                    acB[fj] = __builtin_amdgcn_mfma_f32_16x16x32_f16(a, b, acB[fj], 0, 0, 0);
                }
            }
            #pragma unroll
            for (int fj = 0; fj < 2; ++fj)
            #pragma unroll
            for (int r = 0; r < 4; ++r){
                int rowL = quad + r;
                u_lds[(wave*16 + rowL)*33 + fj*16 + r15] = acB[fj][r];
            }
        }
        __syncthreads();

        float hn0, hn1;
        {   // elementwise: 2 elems/thread; c in registers; scoped (coherent) loads
            #pragma unroll
            for (int e = 0; e < 2; ++e){
                int rowX = rowE + e*8;
                int growX = e ? growE1 : growE0;
                float cv = e ? creg1 : creg0;
                float u0 = u_lds[(0*16 + rowX)*33 + colE];
                float u1 = u_lds[(1*16 + rowX)*33 + colE];
                float u2 = u_lds[(2*16 + rowX)*33 + colE];
                float e0 = __expf(tanhf_(u0*cv + ba));
                float e1 = __expf(tanhf_(u1*cv + ba));
                float e2 = __expf(tanhf_(u2*cv + ba));
                float inv = 1.f/(e0 + e1 + e2);
                size_t lidx = ((size_t)c2*Bb + growX)*32 + colE;   // within stream chunk
                float l0 = h2f(ld_u16s(&A.l16[(size_t)(0*16)*Bb*32 + lidx]));
                float l1 = h2f(ld_u16s(&A.l16[(size_t)(1*16)*Bb*32 + lidx]));
                float l2 = h2f(ld_u16s(&A.l16[(size_t)(2*16)*Bb*32 + lidx]));
                size_t fidx = (size_t)((g*2 + 0)*8 + cfoE)*4096 + (size_t)(growX - grow0)*64 + colF;
                size_t oidx = (size_t)((g*2 + 1)*8 + cfoE)*4096 + (size_t)(growX - grow0)*64 + colF;
                float fg = h2f(ld_u16s(&A.fo16[fidx]));
                float og = h2f(ld_u16s(&A.fo16[oidx]));
                float L = (e0*l0 + e1*l1 + e2*l2)*inv;
                float cn = fg*cv + L;
                float hn = og*tanhf_(cn);
                if (e) creg1 = cn; else creg0 = cn;
                __builtin_nontemporal_store(hn, &A.out[(size_t)BH + ((size_t)growX*Tt + t)*Hh + gcol]);
                if (t == Tt - 1) __builtin_nontemporal_store(hn, &A.out[(size_t)growX*Hh + gcol]);
                if (e) hn1 = hn; else hn0 = hn;
            }
        }
        __syncthreads();                       // everyone done reading u_lds
        {   // repack h tile to fp16 and store into block-exclusive chunk
            srep[rowE*32 + colE]      = f2h(hn0);
            srep[(rowE+8)*32 + colE]  = f2h(hn1);
            __syncthreads();
            uint32_t* dst = (uint32_t*)A.hbf + ((size_t)c2*Bb + grow0 + rs*16)*16;
            int lr = tid >> 4, cp = tid & 15;
            st_u32(dst + (size_t)lr*16 + cp, ((const uint32_t*)srep)[tid]);
        }

        if (t != Tt - 1) group_barrier(gflags, gb, (uint32_t)(2*t + 2));
    }
}

extern "C" void kernel_launch(void* const* d_in, const int* in_sizes, int n_in,
                              void* d_out, int out_size, void* d_ws, size_t ws_size,
                              hipStream_t stream){
    const float* in[29];
    for (int i = 0; i < 29; ++i) in[i] = (const float*)d_in[i];

    char* ws = (char*)d_ws;
    ushort_t* wpack = (ushort_t*)(ws + 0);         // 5,898,240 B (fp16)
    ushort_t* h16   = (ushort_t*)(ws + 5898240);   //   262,144 B (chunked fp16)
    ushort_t* l16   = (ushort_t*)(ws + 6160384);   //   786,432 B (chunked fp16)
    ushort_t* fo16  = (ushort_t*)(ws + 6946816);   //   524,288 B (chunked fp16)
    uint32_t* bar   = (uint32_t*)(ws + 7471104);   //    32,768 B (padded flags)
    // total ~7.5 MB of d_ws

    // mats: 0:i 1:i_p 2:i_n 3:f 4:c 5:c_p 6:c_n 7:o (K=640, [W;U]) ; 8: W_a (K=512)
    static const int WI[9] = {0, 3, 6, 9, 12, 15, 18, 21, 24};
    static const int UI[9] = {1, 4, 7, 10, 13, 16, 19, 22, -1};
    for (int m = 0; m < 9; ++m){
        int Ktot = (m == 8) ? Hh : KGATE;
        const float* Um = (m == 8) ? nullptr : in[UI[m]];
        int groups = Ktot*64;
        pack_mat<<<dim3((groups + 255)/256), dim3(256), 0, stream>>>(
            in[WI[m]], Um, Ktot, wpack + (size_t)m*MATSZ);
    }
    init_state2<<<dim3(BH/256), dim3(256), 0, stream>>>(h16, bar);

    PK pk;
    pk.wpack = wpack;
    pk.X0 = in[26]; pk.X1 = in[27]; pk.X2 = in[28];
    pk.bC0 = in[14]; pk.bC1 = in[17]; pk.bC2 = in[20];
    pk.bI0 = in[2];  pk.bI1 = in[5];  pk.bI2 = in[8];
    pk.bF = in[11]; pk.bO = in[23]; pk.b_a = in[25];
    pk.hbf = h16; pk.l16 = l16; pk.fo16 = fo16;
    pk.bar = bar; pk.out = (float*)d_out;

    hipFuncSetAttribute((const void*)lstm_persistent,
                        hipFuncAttributeMaxDynamicSharedMemorySize, LDSB);
    void* args[] = { &pk };
    hipLaunchCooperativeKernel((const void*)lstm_persistent,
                               dim3(256), dim3(256), args, LDSB, stream);
}

// Round 18
// 9491.747 us; speedup vs baseline: 1.3960x; 1.0068x over previous
//
#include <hip/hip_runtime.h>
#include <cstdint>

#define Bb 256
#define Tt 512
#define Dd 128
#define Hh 512
#define BH (Bb*Hh)            // 131072
#define BTD ((size_t)Bb*Tt*Dd)   // 16,777,216 per stream
#define KGATE 640
#define NCT (Hh/16)           // 32 col-tiles per matrix
#define MATSZ (KGATE*Hh)      // 327680 elements per gate matrix slot
#define LDSB (81920 + 32768 + 3*16*33*4)   // 121,024 B — proven working size

typedef unsigned short ushort_t;
typedef _Float16 h16x8 __attribute__((ext_vector_type(8)));
typedef unsigned short u16x8 __attribute__((ext_vector_type(8)));
typedef float f32x4 __attribute__((ext_vector_type(4)));

static __device__ inline ushort_t f2h(float f){
    _Float16 h = (_Float16)f;
    return __builtin_bit_cast(ushort_t, h);
}
static __device__ inline float h2f(ushort_t u){
    return (float)__builtin_bit_cast(_Float16, u);
}
static __device__ inline float sigmoidf_(float x){ return 1.f/(1.f+__expf(-x)); }
static __device__ inline float tanhf_(float x){
    float ax = fabsf(x);
    float t = __expf(-2.f*ax);
    float r = (1.f - t)/(1.f + t);
    return copysignf(r, x);
}
static __device__ inline h16x8 load_x_frag(const float* xp){
    f32x4 v0 = *reinterpret_cast<const f32x4*>(xp);
    f32x4 v1 = *reinterpret_cast<const f32x4*>(xp + 4);
    u16x8 tmp;
    #pragma unroll
    for (int j = 0; j < 4; ++j){ tmp[j] = f2h(v0[j]); tmp[4+j] = f2h(v1[j]); }
    return __builtin_bit_cast(h16x8, tmp);
}

// ---- device-coherent (agent-scope, relaxed) accessors — R16-proven family ----
static __device__ inline void st_u32(uint32_t* p, uint32_t v){
    __hip_atomic_store(p, v, __ATOMIC_RELAXED, __HIP_MEMORY_SCOPE_AGENT);
}
static __device__ inline uint32_t ld_u32(const uint32_t* p){
    return __hip_atomic_load(p, __ATOMIC_RELAXED, __HIP_MEMORY_SCOPE_AGENT);
}
static __device__ inline ushort_t ld_u16s(const ushort_t* p){
    return __hip_atomic_load(p, __ATOMIC_RELAXED, __HIP_MEMORY_SCOPE_AGENT);
}
static __device__ inline h16x8 ld_frag32(const uint32_t* q){
    union { uint32_t w[4]; h16x8 v; } u;
    u.w[0] = ld_u32(q + 0); u.w[1] = ld_u32(q + 1);
    u.w[2] = ld_u32(q + 2); u.w[3] = ld_u32(q + 3);
    return u.v;
}

// Pack one weight matrix (optionally stacked [W(128 rows); U(512 rows)]) into
// MFMA B-fragment order (fp16): elem(lane,j) = M[kb*32 + (lane>>4)*8 + j][ct*16 + (lane&15)]
__global__ void pack_mat(const float* __restrict__ Wm, const float* __restrict__ Um,
                         int Ktot, ushort_t* __restrict__ dst){
    int total = Ktot * 64;  // groups of 8 fp16
    for (int g = blockIdx.x*blockDim.x + threadIdx.x; g < total; g += gridDim.x*blockDim.x){
        int kb   = g >> 11;
        int rem  = g & 2047;
        int ct   = rem >> 6;
        int lane = rem & 63;
        int k0   = kb*32 + ((lane >> 4) << 3);
        int col  = (ct << 4) + (lane & 15);
        u16x8 o8;
        #pragma unroll
        for (int j = 0; j < 8; ++j){
            int k = k0 + j;
            float v;
            if (Um) v = (k < Dd) ? Wm[k*Hh + col] : Um[(k - Dd)*Hh + col];
            else    v = Wm[k*Hh + col];
            o8[j] = f2h(v);
        }
        *reinterpret_cast<u16x8*>(dst + (size_t)g*8) = o8;
    }
}

// One-time X f32 -> fp16 conversion (hoists the per-step cvt out of the loop)
__global__ void conv_x(const float* __restrict__ X, ushort_t* __restrict__ dst, int n8){
    for (int i = blockIdx.x*blockDim.x + threadIdx.x; i < n8; i += gridDim.x*blockDim.x){
        const float* p = X + (size_t)i*8;
        f32x4 v0 = *reinterpret_cast<const f32x4*>(p);
        f32x4 v1 = *reinterpret_cast<const f32x4*>(p + 4);
        u16x8 o8;
        #pragma unroll
        for (int j = 0; j < 4; ++j){ o8[j] = f2h(v0[j]); o8[4+j] = f2h(v1[j]); }
        *reinterpret_cast<u16x8*>(dst + (size_t)i*8) = o8;
    }
}

__global__ void init_state2(ushort_t* h16, uint32_t* bar){
    int i = blockIdx.x*blockDim.x + threadIdx.x;
    if (i < BH) h16[i] = 0;
    if (i < 8192) bar[i] = 0;   // 4 groups x 64 block-flags x 32 u32 padding
}

struct PK {
    const ushort_t* wpack;
    const float* X0; const float* X1; const float* X2;
    const ushort_t* xh;   // fp16 X, 3 streams contiguous (may be null)
    const float* bC0; const float* bC1; const float* bC2;
    const float* bI0; const float* bI1; const float* bI2;
    const float* bF; const float* bO; const float* b_a;
    ushort_t* hbf;    // fp16, chunked [16 c2][256 rows][32 cols]
    ushort_t* l16;    // fp16, chunked [3 s][16 cs][256 rows][32 cols]
    ushort_t* fo16;   // fp16, chunked [4 g][2 fu][8 cfo][64 rows][64 cols]
    uint32_t* bar; float* out;
};

// Fence-free flag barrier (R16-proven): flags padded to 128B; producers'
// agent-scope write-through stores are drained by the vmcnt(0) the compiler
// emits before s_barrier, so data is at MALL before the flag publish.
// Consumers read exchange buffers with agent-scope relaxed loads — no
// L2-invalidate fence. Workgroup fences are compile-time ordering only.
static __device__ inline void group_barrier(uint32_t* gflags, int gb, uint32_t val){
    __builtin_amdgcn_fence(__ATOMIC_RELEASE, "workgroup");
    __syncthreads();
    if (threadIdx.x == 0) st_u32(&gflags[gb*32], val);
    if (threadIdx.x < 64){
        while (ld_u32(&gflags[threadIdx.x*32]) < val)
            __builtin_amdgcn_s_sleep(1);
    }
    __syncthreads();
    __builtin_amdgcn_fence(__ATOMIC_ACQUIRE, "workgroup");
}

// 256 blocks x 256 threads, cooperative. Group g = bid>>6 owns batch rows [g*64, g*64+64).
// gb 0..47: paired gate blocks (stream s=gb>>4, 32-col slice cs=gb&15): c-mat + i-mat.
// gb 48..55: f-gate (64-col slice). gb 56..63: o-gate (64-col slice).
// Phase B (all blocks): rows rs*16, cols c2*32; c state in registers.
template<int XH>
__global__ __launch_bounds__(256, 1) void lstm_persistent(PK A){
    extern __shared__ char lds[];
    ushort_t* Wlds  = (ushort_t*)lds;                    // 81920 B
    ushort_t* WaLds = (ushort_t*)(lds + 81920);          // 32768 B
    float*    u_lds = (float*)(lds + 81920 + 32768);     // scratch: 6336 B
    ushort_t* srep  = (ushort_t*)u_lds;                  // u16 repack view (max 4096 B used)

    const int bid = blockIdx.x;
    const int g   = bid >> 6;
    const int gb  = bid & 63;
    const int tid = threadIdx.x;
    const int lane = tid & 63;
    const int wave = tid >> 6;
    const int r15  = lane & 15;
    const int khi  = (lane >> 4) << 3;
    const int quad = (lane >> 4) << 2;
    const int grow0 = g << 6;

    const bool paired = (gb < 48);
    const int s   = gb >> 4;
    const int cs  = gb & 15;
    const int fu  = (gb >= 56) ? 1 : 0;
    const int cfo = (gb - 48) & 7;

    const uint32_t* hbf32 = (const uint32_t*)A.hbf;
    const uint32_t* l32   = (const uint32_t*)A.l16;

    // ---- stage weights into LDS (once) ----
    if (paired){
        const ushort_t* base0 = A.wpack + (size_t)(4 + s)*MATSZ;  // c-mat
        const ushort_t* base1 = A.wpack + (size_t)s*MATSZ;        // i-mat
        for (int u = tid; u < 80*64; u += 256){
            int ch = u >> 6, un = u & 63;
            int m2 = (ch >= 40) ? 1 : 0;
            int rem = ch - m2*40;
            int kb = rem >> 1, j = rem & 1;
            const ushort_t* src = (m2 == 0 ? base0 : base1)
                                + ((size_t)(kb*NCT + cs*2 + j)*64 + un)*8;
            *reinterpret_cast<u16x8*>(Wlds + ((size_t)ch*64 + un)*8)
                = *reinterpret_cast<const u16x8*>(src);
        }
    } else {
        const ushort_t* base = A.wpack + (size_t)(fu == 0 ? 3 : 7)*MATSZ;
        for (int u = tid; u < 80*64; u += 256){
            int ch = u >> 6, un = u & 63;
            int kb = ch >> 2, j = ch & 3;
            const ushort_t* src = base + ((size_t)(kb*NCT + cfo*4 + j)*64 + un)*8;
            *reinterpret_cast<u16x8*>(Wlds + ((size_t)ch*64 + un)*8)
                = *reinterpret_cast<const u16x8*>(src);
        }
    }
    const int rs = gb >> 4, c2 = gb & 15;   // phase-B tile
    {
        const ushort_t* base = A.wpack + (size_t)8*MATSZ;
        for (int u = tid; u < 32*64; u += 256){
            int ch = u >> 6, un = u & 63;
            int kb = ch >> 1, j = ch & 1;
            const ushort_t* src = base + ((size_t)(kb*NCT + c2*2 + j)*64 + un)*8;
            *reinterpret_cast<u16x8*>(WaLds + ((size_t)ch*64 + un)*8)
                = *reinterpret_cast<const u16x8*>(src);
        }
    }
    __syncthreads();

    // ---- per-thread persistent state ----
    float biasA0[4] = {0,0,0,0}, biasA1[2] = {0,0};
    if (paired){
        const float* bCs = (s == 0) ? A.bC0 : (s == 1) ? A.bC1 : A.bC2;
        const float* bIs = (s == 0) ? A.bI0 : (s == 1) ? A.bI1 : A.bI2;
        #pragma unroll
        for (int fj = 0; fj < 2; ++fj){
            int col = cs*32 + fj*16 + r15;
            biasA0[fj] = bCs[col];
            biasA1[fj] = bIs[col];
        }
    } else {
        const float* bb = fu ? A.bO : A.bF;
        #pragma unroll
        for (int fj = 0; fj < 4; ++fj)
            biasA0[fj] = bb[cfo*64 + fj*16 + r15];
    }
    const int rowE = tid >> 5;          // 0..7
    const int colE = tid & 31;
    const int gcol = c2*32 + colE;
    const int growE0 = grow0 + rs*16 + rowE;
    const int growE1 = growE0 + 8;
    const float ba = A.b_a[gcol];
    float creg0 = 0.f, creg1 = 0.f;

    const float* Xs = paired ? ((s == 0) ? A.X0 : (s == 1) ? A.X1 : A.X2) : A.X0;
    const ushort_t* Xsh = XH ? (A.xh + (size_t)(paired ? s : 0)*BTD) : nullptr;
    uint32_t* gflags = A.bar + g*2048;           // [64][32]
    const int arow = grow0 + wave*16 + r15;

    // elementwise read indices (fp16 chunked buffers)
    const int cfoE = gcol >> 6;          // 64-col chunk for f/o
    const int colF = gcol & 63;

    for (int t = 0; t < Tt; ++t){
        // ================= phase A: gate GEMMs =================
        if (paired){
            f32x4 a0[2] = {{0.f,0.f,0.f,0.f},{0.f,0.f,0.f,0.f}};
            f32x4 a1[2] = {{0.f,0.f,0.f,0.f},{0.f,0.f,0.f,0.f}};
            const float* xp = Xs + ((size_t)arow*Tt + t)*Dd + khi;
            const ushort_t* xhp = XH ? (Xsh + ((size_t)arow*Tt + t)*Dd + khi) : nullptr;
            #pragma unroll
            for (int kb = 0; kb < KGATE/32; ++kb){
                h16x8 a;
                if (kb < 4){
                    if (XH) a = *reinterpret_cast<const h16x8*>(xhp + kb*32);
                    else    a = load_x_frag(xp + kb*32);
                } else {
                    a = ld_frag32(hbf32 + ((((size_t)(kb-4)*Bb + arow)*32 + khi) >> 1));
                }
                #pragma unroll
                for (int fj = 0; fj < 2; ++fj){
                    h16x8 b0 = *reinterpret_cast<const h16x8*>(Wlds + ((size_t)(kb*2 + fj))*512 + lane*8);
                    a0[fj] = __builtin_amdgcn_mfma_f32_16x16x32_f16(a, b0, a0[fj], 0, 0, 0);
                    h16x8 b1 = *reinterpret_cast<const h16x8*>(Wlds + ((size_t)((20 + kb)*2 + fj))*512 + lane*8);
                    a1[fj] = __builtin_amdgcn_mfma_f32_16x16x32_f16(a, b1, a1[fj], 0, 0, 0);
                }
            }
            // repack l (fp16) into LDS (64x32 = 4096 B), then coop full-line scoped stores
            #pragma unroll
            for (int fj = 0; fj < 2; ++fj)
            #pragma unroll
            for (int r = 0; r < 4; ++r){
                int lrow = wave*16 + quad + r;
                float l = tanhf_(a0[fj][r] + biasA0[fj]) * sigmoidf_(a1[fj][r] + biasA1[fj]);
                srep[lrow*32 + fj*16 + r15] = f2h(l);
            }
            __syncthreads();
            {   // block-exclusive chunk [s][cs]: rows grow0..+64, 16 u32/row
                uint32_t* dst = (uint32_t*)A.l16 + ((size_t)(s*16 + cs)*Bb + grow0)*16;
                const uint32_t* src = (const uint32_t*)srep;
                #pragma unroll
                for (int k2 = 0; k2 < 4; ++k2){
                    int idx = tid + k2*256;
                    int lrow = idx >> 4, cp = idx & 15;
                    st_u32(dst + (size_t)lrow*16 + cp, src[idx]);
                }
            }
        } else {
            f32x4 ac[4] = {{0.f,0.f,0.f,0.f},{0.f,0.f,0.f,0.f},{0.f,0.f,0.f,0.f},{0.f,0.f,0.f,0.f}};
            const float* xp = Xs + ((size_t)arow*Tt + t)*Dd + khi;
            const ushort_t* xhp = XH ? (Xsh + ((size_t)arow*Tt + t)*Dd + khi) : nullptr;
            #pragma unroll
            for (int kb = 0; kb < KGATE/32; ++kb){
                h16x8 a;
                if (kb < 4){
                    if (XH) a = *reinterpret_cast<const h16x8*>(xhp + kb*32);
                    else    a = load_x_frag(xp + kb*32);
                } else {
                    a = ld_frag32(hbf32 + ((((size_t)(kb-4)*Bb + arow)*32 + khi) >> 1));
                }
                #pragma unroll
                for (int fj = 0; fj < 4; ++fj){
                    h16x8 b = *reinterpret_cast<const h16x8*>(Wlds + ((size_t)(kb*4 + fj))*512 + lane*8);
                    ac[fj] = __builtin_amdgcn_mfma_f32_16x16x32_f16(a, b, ac[fj], 0, 0, 0);
                }
            }
            // repack f/o in TWO 64x32 passes (4096 B each — fits scratch).
            uint32_t* dstc = (uint32_t*)A.fo16 + (size_t)((g*2 + fu)*8 + cfo)*2048;
            #pragma unroll
            for (int p = 0; p < 2; ++p){
                #pragma unroll
                for (int fj2 = 0; fj2 < 2; ++fj2){
                    int fj = p*2 + fj2;
                    #pragma unroll
                    for (int r = 0; r < 4; ++r){
                        int lrow = wave*16 + quad + r;
                        srep[lrow*32 + fj2*16 + r15] = f2h(sigmoidf_(ac[fj][r] + biasA0[fj]));
                    }
                }
                __syncthreads();
                {   // store 64 rows x 32 cols (16 u32/row) at col-offset p*32 (p*16 u32)
                    const uint32_t* src = (const uint32_t*)srep;
                    #pragma unroll
                    for (int k2 = 0; k2 < 4; ++k2){
                        int idx = tid + k2*256;          // 0..1023
                        int lrow = idx >> 4, cp = idx & 15;
                        st_u32(dstc + (size_t)lrow*32 + p*16 + cp, src[idx]);
                    }
                }
                __syncthreads();   // srep reads done before next pass overwrites
            }
        }

        group_barrier(gflags, gb, (uint32_t)(2*t + 1));

        // ================= phase B: W_a GEMMs + blend + cell update =================
        if (wave < 3){
            f32x4 acB[2] = {{0.f,0.f,0.f,0.f},{0.f,0.f,0.f,0.f}};
            const int brow = grow0 + rs*16 + r15;
            #pragma unroll
            for (int kb = 0; kb < Hh/32; ++kb){
                h16x8 a = ld_frag32(l32 + ((((size_t)(wave*16 + kb)*Bb + brow)*32 + khi) >> 1));
                #pragma unroll
                for (int fj = 0; fj < 2; ++fj){
                    h16x8 b = *reinterpret_cast<const h16x8*>(WaLds + ((size_t)(kb*2 + fj))*512 + lane*8);
                    acB[fj] = __builtin_amdgcn_mfma_f32_16x16x32_f16(a, b, acB[fj], 0, 0, 0);
                }
            }
            #pragma unroll
            for (int fj = 0; fj < 2; ++fj)
            #pragma unroll
            for (int r = 0; r < 4; ++r){
                int rowL = quad + r;
                u_lds[(wave*16 + rowL)*33 + fj*16 + r15] = acB[fj][r];
            }
        }
        __syncthreads();

        float hn0, hn1;
        {   // elementwise: 2 elems/thread; c in registers; scoped (coherent) loads
            #pragma unroll
            for (int e = 0; e < 2; ++e){
                int rowX = rowE + e*8;
                int growX = e ? growE1 : growE0;
                float cv = e ? creg1 : creg0;
                float u0 = u_lds[(0*16 + rowX)*33 + colE];
                float u1 = u_lds[(1*16 + rowX)*33 + colE];
                float u2 = u_lds[(2*16 + rowX)*33 + colE];
                float e0 = __expf(tanhf_(u0*cv + ba));
                float e1 = __expf(tanhf_(u1*cv + ba));
                float e2 = __expf(tanhf_(u2*cv + ba));
                float inv = 1.f/(e0 + e1 + e2);
                size_t lidx = ((size_t)c2*Bb + growX)*32 + colE;   // within stream chunk
                float l0 = h2f(ld_u16s(&A.l16[(size_t)(0*16)*Bb*32 + lidx]));
                float l1 = h2f(ld_u16s(&A.l16[(size_t)(1*16)*Bb*32 + lidx]));
                float l2 = h2f(ld_u16s(&A.l16[(size_t)(2*16)*Bb*32 + lidx]));
                size_t fidx = (size_t)((g*2 + 0)*8 + cfoE)*4096 + (size_t)(growX - grow0)*64 + colF;
                size_t oidx = (size_t)((g*2 + 1)*8 + cfoE)*4096 + (size_t)(growX - grow0)*64 + colF;
                float fg = h2f(ld_u16s(&A.fo16[fidx]));
                float og = h2f(ld_u16s(&A.fo16[oidx]));
                float L = (e0*l0 + e1*l1 + e2*l2)*inv;
                float cn = fg*cv + L;
                float hn = og*tanhf_(cn);
                if (e) creg1 = cn; else creg0 = cn;
                __builtin_nontemporal_store(hn, &A.out[(size_t)BH + ((size_t)growX*Tt + t)*Hh + gcol]);
                if (t == Tt - 1) __builtin_nontemporal_store(hn, &A.out[(size_t)growX*Hh + gcol]);
                if (e) hn1 = hn; else hn0 = hn;
            }
        }
        __syncthreads();                       // everyone done reading u_lds
        {   // repack h tile to fp16 and store into block-exclusive chunk
            srep[rowE*32 + colE]      = f2h(hn0);
            srep[(rowE+8)*32 + colE]  = f2h(hn1);
            __syncthreads();
            uint32_t* dst = (uint32_t*)A.hbf + ((size_t)c2*Bb + grow0 + rs*16)*16;
            int lr = tid >> 4, cp = tid & 15;
            st_u32(dst + (size_t)lr*16 + cp, ((const uint32_t*)srep)[tid]);
        }

        if (t != Tt - 1) group_barrier(gflags, gb, (uint32_t)(2*t + 2));
    }
}

extern "C" void kernel_launch(void* const* d_in, const int* in_sizes, int n_in,
                              void* d_out, int out_size, void* d_ws, size_t ws_size,
                              hipStream_t stream){
    const float* in[29];
    for (int i = 0; i < 29; ++i) in[i] = (const float*)d_in[i];

    char* ws = (char*)d_ws;
    ushort_t* wpack = (ushort_t*)(ws + 0);         // 5,898,240 B (fp16)
    ushort_t* h16   = (ushort_t*)(ws + 5898240);   //   262,144 B (chunked fp16)
    ushort_t* l16   = (ushort_t*)(ws + 6160384);   //   786,432 B (chunked fp16)
    ushort_t* fo16  = (ushort_t*)(ws + 6946816);   //   524,288 B (chunked fp16)
    uint32_t* bar   = (uint32_t*)(ws + 7471104);   //    32,768 B (padded flags)
    ushort_t* xh    = (ushort_t*)(ws + 7503872);   // 100,663,296 B (fp16 X, optional)
    const bool use_xh = (ws_size >= (size_t)7503872 + 3*BTD*sizeof(ushort_t));

    // mats: 0:i 1:i_p 2:i_n 3:f 4:c 5:c_p 6:c_n 7:o (K=640, [W;U]) ; 8: W_a (K=512)
    static const int WI[9] = {0, 3, 6, 9, 12, 15, 18, 21, 24};
    static const int UI[9] = {1, 4, 7, 10, 13, 16, 19, 22, -1};
    for (int m = 0; m < 9; ++m){
        int Ktot = (m == 8) ? Hh : KGATE;
        const float* Um = (m == 8) ? nullptr : in[UI[m]];
        int groups = Ktot*64;
        pack_mat<<<dim3((groups + 255)/256), dim3(256), 0, stream>>>(
            in[WI[m]], Um, Ktot, wpack + (size_t)m*MATSZ);
    }
    if (use_xh){
        for (int m = 0; m < 3; ++m)
            conv_x<<<dim3(2048), dim3(256), 0, stream>>>(
                in[26 + m], xh + (size_t)m*BTD, (int)(BTD/8));
    }
    init_state2<<<dim3(BH/256), dim3(256), 0, stream>>>(h16, bar);

    PK pk;
    pk.wpack = wpack;
    pk.X0 = in[26]; pk.X1 = in[27]; pk.X2 = in[28];
    pk.xh = use_xh ? xh : nullptr;
    pk.bC0 = in[14]; pk.bC1 = in[17]; pk.bC2 = in[20];
    pk.bI0 = in[2];  pk.bI1 = in[5];  pk.bI2 = in[8];
    pk.bF = in[11]; pk.bO = in[23]; pk.b_a = in[25];
    pk.hbf = h16; pk.l16 = l16; pk.fo16 = fo16;
    pk.bar = bar; pk.out = (float*)d_out;

    void* args[] = { &pk };
    if (use_xh){
        hipFuncSetAttribute((const void*)lstm_persistent<1>,
                            hipFuncAttributeMaxDynamicSharedMemorySize, LDSB);
        hipLaunchCooperativeKernel((const void*)lstm_persistent<1>,
                                   dim3(256), dim3(256), args, LDSB, stream);
    } else {
        hipFuncSetAttribute((const void*)lstm_persistent<0>,
                            hipFuncAttributeMaxDynamicSharedMemorySize, LDSB);
        hipLaunchCooperativeKernel((const void*)lstm_persistent<0>,
                                   dim3(256), dim3(256), args, LDSB, stream);
    }
}